// Round 3
// baseline (410.247 us; speedup 1.0000x reference)
//
#include <hip/hip_runtime.h>
#include <hip/hip_bf16.h>

// TimeFeatureEmbedding: y[b,t,d] = sum_e x[b,t,e]*W[d,e] + b[d], broadcast to
// [B,T,S,D]. D=512, d_inp=4, S=64. 402.7 MB fp32 stores -> write-BW-bound.
//
// R2 post-mortem: flat grid-stride with an in-loop x load ran at 2.7 TB/s vs
// the harness fill kernel's 6.33 TB/s. Cause: loads and stores share the
// in-order vmcnt counter, so the s_waitcnt for each iteration's load also
// waits for the previous iteration's store to be ACKed by L2 -> one store
// per write-ack-latency per wave, no overlap. Fix: precompute all 48
// per-thread y values into registers (192 VGPR), then run a pure store loop
// with ZERO loads -> no vmcnt waits, streams like the fill kernel.

#define D_MODEL 512
#define D_INP   4

template<int ITERS>
__global__ __launch_bounds__(256, 1) void tfe_reg(
    const float4* __restrict__ x4,   // [BT]  x rows as float4
    const float4* __restrict__ W4,   // [512] each W row is one float4
    const float4* __restrict__ b4,   // [128] bias as float4
    float4* __restrict__ out4,       // flat output as float4
    int btShift)                     // log2(S*128); S=64 -> 13
{
    const size_t stride = (size_t)gridDim.x * 256;        // 524288 float4
    const size_t f0 = (size_t)blockIdx.x * 256 + threadIdx.x;
    const int d4 = (int)(f0 & 127);                       // stride%128==0
    const int btStep = (int)(stride >> btShift);          // 64
    const int bt0 = (int)(f0 >> btShift);                 // block-uniform

    const float4 w0 = W4[4 * d4 + 0];
    const float4 w1 = W4[4 * d4 + 1];
    const float4 w2 = W4[4 * d4 + 2];
    const float4 w3 = W4[4 * d4 + 3];
    const float4 bv = b4[d4];

    // Phase 1: compute all ITERS y-values into registers (no spills:
    // launch_bounds(256,1) allows up to 512 VGPR; y uses 192).
    float4 y[ITERS];
#pragma unroll
    for (int i = 0; i < ITERS; ++i) {
        const float4 xv = x4[bt0 + i * btStep];  // wave-uniform 16B, L2-hit
        y[i].x = fmaf(xv.x, w0.x, fmaf(xv.y, w0.y, fmaf(xv.z, w0.z, fmaf(xv.w, w0.w, bv.x))));
        y[i].y = fmaf(xv.x, w1.x, fmaf(xv.y, w1.y, fmaf(xv.z, w1.z, fmaf(xv.w, w1.w, bv.y))));
        y[i].z = fmaf(xv.x, w2.x, fmaf(xv.y, w2.y, fmaf(xv.z, w2.z, fmaf(xv.w, w2.w, bv.z))));
        y[i].w = fmaf(xv.x, w3.x, fmaf(xv.y, w3.y, fmaf(xv.z, w3.z, fmaf(xv.w, w3.w, bv.w))));
    }

    __syncthreads();  // separate phases; all loads drained before store loop

    // Phase 2: pure store stream — zero loads, zero vmcnt waits in loop.
    size_t f = f0;
#pragma unroll
    for (int i = 0; i < ITERS; ++i, f += stride) {
        out4[f] = y[i];
    }
}

// Generic fallback (any S / sizes): flat grid-stride with in-loop load.
__global__ __launch_bounds__(256) void tfe_flat(
    const float4* __restrict__ x4, const float4* __restrict__ W4,
    const float4* __restrict__ b4, float4* __restrict__ out4,
    size_t N4, int rowLen /* S*128 */)
{
    const size_t stride = (size_t)gridDim.x * blockDim.x;
    for (size_t f = (size_t)blockIdx.x * blockDim.x + threadIdx.x; f < N4; f += stride) {
        const int d4 = (int)(f & 127);
        const int bt = (int)(f / (size_t)rowLen);
        const float4 xv = x4[bt];
        const float4 w0 = W4[4 * d4 + 0];
        const float4 w1 = W4[4 * d4 + 1];
        const float4 w2 = W4[4 * d4 + 2];
        const float4 w3 = W4[4 * d4 + 3];
        const float4 bv = b4[d4];
        float4 y;
        y.x = fmaf(xv.x, w0.x, fmaf(xv.y, w0.y, fmaf(xv.z, w0.z, fmaf(xv.w, w0.w, bv.x))));
        y.y = fmaf(xv.x, w1.x, fmaf(xv.y, w1.y, fmaf(xv.z, w1.z, fmaf(xv.w, w1.w, bv.y))));
        y.z = fmaf(xv.x, w2.x, fmaf(xv.y, w2.y, fmaf(xv.z, w2.z, fmaf(xv.w, w2.w, bv.z))));
        y.w = fmaf(xv.x, w3.x, fmaf(xv.y, w3.y, fmaf(xv.z, w3.z, fmaf(xv.w, w3.w, bv.w))));
        out4[f] = y;
    }
}

extern "C" void kernel_launch(void* const* d_in, const int* in_sizes, int n_in,
                              void* d_out, int out_size, void* d_ws, size_t ws_size,
                              hipStream_t stream) {
    const float* x    = (const float*)d_in[0];   // [B,T,4] fp32
    const float* W    = (const float*)d_in[2];   // [512,4] fp32
    const float* bias = (const float*)d_in[3];   // [512]   fp32
    float* out        = (float*)d_out;

    const int BT = in_sizes[0] / D_INP;               // 3072
    const int S  = out_size / (BT * D_MODEL);         // 64
    const size_t N4 = (size_t)out_size / 4;           // 25,165,824 float4

    const int GRID = 2048;                            // 8 blocks/CU nominal
    const size_t stride = (size_t)GRID * 256;         // 524,288

    bool pow2S = (S & (S - 1)) == 0;
    if (pow2S && N4 % stride == 0 && (N4 / stride) == 48 &&
        (stride % (size_t)(S * (D_MODEL / 4))) == 0) {
        int btShift = 0, v = S * (D_MODEL / 4);
        while ((1 << (btShift + 1)) <= v) ++btShift;  // 13 for S=64
        tfe_reg<48><<<GRID, 256, 0, stream>>>(
            (const float4*)x, (const float4*)W, (const float4*)bias,
            (float4*)out, btShift);
    } else {
        tfe_flat<<<GRID, 256, 0, stream>>>(
            (const float4*)x, (const float4*)W, (const float4*)bias,
            (float4*)out, N4, S * (D_MODEL / 4));
    }
}